// Round 1
// baseline (411.491 us; speedup 1.0000x reference)
//
#include <hip/hip_runtime.h>
#include <math.h>

// Problem constants
constexpr int Bq = 128;   // batch
constexpr int Nn = 512;   // nodes
constexpr int Dd = 300;   // feature dim
constexpr int Aa = 32;    // attention dim
constexpr int DT = 304;   // d padded to 19 tiles of 16 for MFMA N-dim

typedef __attribute__((ext_vector_type(8))) short short8;   // 8 bf16 (4 VGPRs)
typedef __attribute__((ext_vector_type(4))) float float4v;  // MFMA acc

static __device__ __forceinline__ ushort f2bf(float x) {
    unsigned u = __float_as_uint(x);
    return (ushort)((u + 0x7FFF + ((u >> 16) & 1)) >> 16);   // RNE
}

// ---------------- Kernel 1: Q/K projection (bf16 out) + bf16 X^T emission ----------------
constexpr int KB_ROWS = 128;
constexpr int DCHUNK = 100;      // 300 = 3 x 100
constexpr int XS_STRIDE = 102;

__global__ __launch_bounds__(256) void proj_qk(
    const float* __restrict__ X, const float* __restrict__ Wq,
    const float* __restrict__ Wk, ushort* __restrict__ Qo, ushort* __restrict__ Ko,
    ushort* __restrict__ XbfT)
{
    __shared__ float xs[KB_ROWS * XS_STRIDE];  // ~51 KB
    const int b  = blockIdx.y;
    const int n0 = blockIdx.x * KB_ROWS;
    const int t  = threadIdx.x;
    const int c  = t & 15;
    const int r  = t >> 4;
    const int a4 = c * 4;
    const int rbase = r * 8;
    const float* Wbase = (a4 < Aa) ? (Wq + a4) : (Wk + (a4 - Aa));
    const float* Xb = X + ((size_t)(b * Nn + n0)) * Dd;

    float4 acc[8];
#pragma unroll
    for (int j = 0; j < 8; ++j) acc[j] = make_float4(0.f, 0.f, 0.f, 0.f);

    for (int d0 = 0; d0 < Dd; d0 += DCHUNK) {
        for (int l = t; l < KB_ROWS * (DCHUNK / 2); l += 256) {
            int row = l / (DCHUNK / 2);
            int dd2 = l - row * (DCHUNK / 2);
            *(float2*)(xs + row * XS_STRIDE + dd2 * 2) =
                *(const float2*)(Xb + (size_t)row * Dd + d0 + dd2 * 2);
        }
        __syncthreads();
        for (int dd = 0; dd < DCHUNK; ++dd) {
            float4 w4 = *(const float4*)(Wbase + (size_t)(d0 + dd) * Aa);
#pragma unroll
            for (int j = 0; j < 8; ++j) {
                float xv = xs[(rbase + j) * XS_STRIDE + dd];
                acc[j].x += xv * w4.x; acc[j].y += xv * w4.y;
                acc[j].z += xv * w4.z; acc[j].w += xv * w4.w;
            }
        }
        // emit bf16 transposed chunk: XbfT[b][d0+dd][n0+row]
        for (int l = t; l < KB_ROWS * DCHUNK; l += 256) {
            int dd  = l >> 7;        // 12800 = 100 x 128
            int row = l & 127;
            XbfT[((size_t)b * DT + d0 + dd) * Nn + n0 + row] =
                f2bf(xs[row * XS_STRIDE + dd]);
        }
        __syncthreads();
    }

    ushort* Obase = (a4 < Aa) ? (Qo + a4) : (Ko + (a4 - Aa));
#pragma unroll
    for (int j = 0; j < 8; ++j) {
        int n = n0 + rbase + j;
        ushort4 o;
        o.x = f2bf(acc[j].x); o.y = f2bf(acc[j].y);
        o.z = f2bf(acc[j].z); o.w = f2bf(acc[j].w);
        *(ushort4*)(Obase + (size_t)(b * Nn + n) * Aa) = o;
    }
}

// ---------------- Kernel 2: all-MFMA scores + softmax + MFMA aggregation ----------------
// One block per (b, 32-row tile). 256 threads. XCD-swizzled 1-D grid.
// v2: adjacency streamed+ballot'd into a 2.3KB LDS bitmask (kills the per-fragment
//     scalar HBM load chain); paired d-tiles in phase 3 (2x MLP); launch_bounds(256,4)
//     for 4 blocks/CU; denominator folded past the single barrier.
constexpr int TN = 32;

__global__ __launch_bounds__(256, 4) void attn_kernel(
    const float* __restrict__ Adj, const ushort* __restrict__ Qbf,
    const ushort* __restrict__ Kbf, const ushort* __restrict__ XbfT,
    float* __restrict__ Out)
{
    __shared__ __align__(16) ushort fragA[2 * 8192];       // 32 KB, frag-packed e values
    __shared__ unsigned long long abits[TN][9];            // ballot bitmask; stride 9 kills 4-way bank conflict
    __shared__ float wsum[4][TN];

    // XCD swizzle: each XCD (blk%8) streams all 16 tiles of one batch consecutively
    const int blk  = blockIdx.x;
    const int b    = ((blk >> 7) << 3) | (blk & 7);
    const int n0   = ((blk >> 3) & 15) * TN;

    const int t    = threadIdx.x;
    const int lane = t & 63;
    const int wv   = t >> 6;
    const int dl   = lane & 15;
    const int quad = lane >> 4;

    // Q fragments early (independent of adjacency staging; loads fly during phase 0)
    short8 qfr[2];
#pragma unroll
    for (int rs = 0; rs < 2; ++rs)
        qfr[rs] = *(const short8*)(Qbf + ((size_t)(b * Nn + n0 + rs * 16 + dl)) * Aa + quad * 8);

    // ---- Phase 0: adjacency tile -> LDS bitmask via coalesced float4 stream + ballot ----
    // Lane l covers cols {4l+j} (word j, bit l) per 256-col half-row: word = h*4+j, bit = (c&255)>>2.
    {
        const float* adjT = Adj + ((size_t)b * Nn + n0) * Nn;
#pragma unroll 4
        for (int rr = 0; rr < 8; ++rr) {
            const int row = wv * 8 + rr;
            const float* ap = adjT + (size_t)row * Nn + lane * 4;
            float4 v0 = *(const float4*)ap;
            float4 v1 = *(const float4*)(ap + 256);
            unsigned long long b0 = __ballot(v0.x != 0.f);
            unsigned long long b1 = __ballot(v0.y != 0.f);
            unsigned long long b2 = __ballot(v0.z != 0.f);
            unsigned long long b3 = __ballot(v0.w != 0.f);
            unsigned long long b4 = __ballot(v1.x != 0.f);
            unsigned long long b5 = __ballot(v1.y != 0.f);
            unsigned long long b6 = __ballot(v1.z != 0.f);
            unsigned long long b7 = __ballot(v1.w != 0.f);
            if (lane == 0) {
                abits[row][0] = b0; abits[row][1] = b1;
                abits[row][2] = b2; abits[row][3] = b3;
                abits[row][4] = b4; abits[row][5] = b5;
                abits[row][6] = b6; abits[row][7] = b7;
            }
        }
    }
    __syncthreads();

    // ---- Phase 1: S = Q K^T via MFMA; e = bit ? exp(S) : 1 -> fragA (bf16) ----
    float dsum[2][4];
#pragma unroll
    for (int rs = 0; rs < 2; ++rs)
#pragma unroll
        for (int r = 0; r < 4; ++r) dsum[rs][r] = 0.f;

    const int jw  = dl & 3;    // ballot word within half-row
    const int sh0 = dl >> 2;   // bit base; full shift = (ks&7)*8 + sh0 (a0), +4 (a1)

#pragma unroll 2
    for (int ks = wv; ks < 16; ks += 4) {
        const int m0 = ks * 32;
        short8 kf0 = *(const short8*)(Kbf + ((size_t)(b * Nn + m0 + dl)) * Aa + quad * 8);
        short8 kf1 = *(const short8*)(Kbf + ((size_t)(b * Nn + m0 + 16 + dl)) * Aa + quad * 8);
        // writer target: elem = rs*8192 + (ks*64 + q2*16 + ii)*8 + jj
        ushort* wp = fragA + ks * 512 + (dl >> 3) * 128 + (dl & 7);
        const int wofs = (ks >> 3) * 4 + jw;      // cols m0..m0+31 all live in one uint64 word
        const int shb  = (ks & 7) * 8 + sh0;
#pragma unroll
        for (int rs = 0; rs < 2; ++rs) {
            float4v z = {0.f, 0.f, 0.f, 0.f};
            float4v acc0 = __builtin_amdgcn_mfma_f32_16x16x32_bf16(qfr[rs], kf0, z, 0, 0, 0);
            float4v acc1 = __builtin_amdgcn_mfma_f32_16x16x32_bf16(qfr[rs], kf1, z, 0, 0, 0);
            ushort* wpr = wp + rs * 8192;
            const int rbase = rs * 16 + quad * 4;
#pragma unroll
            for (int r = 0; r < 4; ++r) {
                unsigned long long w = abits[rbase + r][wofs];   // 4-lane broadcast, conflict-free
                float e0 = ((w >> shb) & 1ull)       ? __expf(acc0[r]) : 1.0f;  // adj==0 -> e=1 exactly
                float e1 = ((w >> (shb + 4)) & 1ull) ? __expf(acc1[r]) : 1.0f;
                dsum[rs][r] += e0 + e1;
                ushort* w2 = wpr + (quad * 4 + r) * 8;
                w2[0]   = f2bf(e0);
                w2[256] = f2bf(e1);
            }
        }
    }

    // ---- Phase 2: per-wave partial denominators -> wsum (single barrier with fragA) ----
#pragma unroll
    for (int rs = 0; rs < 2; ++rs)
#pragma unroll
        for (int r = 0; r < 4; ++r) {
            float v = dsum[rs][r];
            v += __shfl_xor(v, 1);
            v += __shfl_xor(v, 2);
            v += __shfl_xor(v, 4);
            v += __shfl_xor(v, 8);
            if (dl == 0) wsum[wv][rs * 16 + quad * 4 + r] = v;
        }
    __syncthreads();

    // Each lane finishes the reduction itself (broadcast LDS reads, no extra barrier)
    float inv0[4], inv1[4];
#pragma unroll
    for (int r = 0; r < 4; ++r) {
        const int rw = quad * 4 + r;
        inv0[r] = 1.0f / (wsum[0][rw] + wsum[1][rw] + wsum[2][rw] + wsum[3][rw]);
        inv1[r] = 1.0f / (wsum[0][16 + rw] + wsum[1][16 + rw] + wsum[2][16 + rw] + wsum[3][16 + rw]);
    }

    // ---- Phase 3: Out[i][d] = inv[i] * sum_m e[i][m] * X[m][d] via MFMA ----
    // Paired d-tiles: 2 independent X-load->MFMA chains per wave, P-frag LDS reads amortized.
    const ushort* Xb  = XbfT + ((size_t)b * DT) * Nn;
    const ushort* afp = fragA + (size_t)lane * 8;

    for (int p = 0; p < 3; ++p) {
        const int dta = wv + p * 8;
        if (dta >= DT / 16) break;
        const int dtb = dta + 4;
        if (dtb < DT / 16) {
            const ushort* bba = Xb + (size_t)(dta * 16 + dl) * Nn + quad * 8;
            const ushort* bbb = Xb + (size_t)(dtb * 16 + dl) * Nn + quad * 8;
            float4v a0a = {0.f, 0.f, 0.f, 0.f};
            float4v a1a = {0.f, 0.f, 0.f, 0.f};
            float4v a0b = {0.f, 0.f, 0.f, 0.f};
            float4v a1b = {0.f, 0.f, 0.f, 0.f};
#pragma unroll
            for (int ks = 0; ks < 16; ++ks) {
                short8 bfa = *(const short8*)(bba + ks * 32);
                short8 bfb = *(const short8*)(bbb + ks * 32);
                short8 p0  = *(const short8*)(afp + ks * 512);
                short8 p1  = *(const short8*)(afp + 8192 + ks * 512);
                a0a = __builtin_amdgcn_mfma_f32_16x16x32_bf16(p0, bfa, a0a, 0, 0, 0);
                a1a = __builtin_amdgcn_mfma_f32_16x16x32_bf16(p1, bfa, a1a, 0, 0, 0);
                a0b = __builtin_amdgcn_mfma_f32_16x16x32_bf16(p0, bfb, a0b, 0, 0, 0);
                a1b = __builtin_amdgcn_mfma_f32_16x16x32_bf16(p1, bfb, a1b, 0, 0, 0);
            }
            {
                const int d = dta * 16 + dl;
                if (d < Dd) {
#pragma unroll
                    for (int r = 0; r < 4; ++r) {
                        Out[((size_t)(b * Nn + n0 + quad * 4 + r)) * Dd + d]      = a0a[r] * inv0[r];
                        Out[((size_t)(b * Nn + n0 + 16 + quad * 4 + r)) * Dd + d] = a1a[r] * inv1[r];
                    }
                }
            }
            {
                const int d = dtb * 16 + dl;
                if (d < Dd) {
#pragma unroll
                    for (int r = 0; r < 4; ++r) {
                        Out[((size_t)(b * Nn + n0 + quad * 4 + r)) * Dd + d]      = a0b[r] * inv0[r];
                        Out[((size_t)(b * Nn + n0 + 16 + quad * 4 + r)) * Dd + d] = a1b[r] * inv1[r];
                    }
                }
            }
        } else {
            const ushort* bb = Xb + (size_t)(dta * 16 + dl) * Nn + quad * 8;
            float4v acc0 = {0.f, 0.f, 0.f, 0.f};
            float4v acc1 = {0.f, 0.f, 0.f, 0.f};
#pragma unroll
            for (int ks = 0; ks < 16; ++ks) {
                short8 bf = *(const short8*)(bb + ks * 32);
                short8 p0 = *(const short8*)(afp + ks * 512);
                short8 p1 = *(const short8*)(afp + 8192 + ks * 512);
                acc0 = __builtin_amdgcn_mfma_f32_16x16x32_bf16(p0, bf, acc0, 0, 0, 0);
                acc1 = __builtin_amdgcn_mfma_f32_16x16x32_bf16(p1, bf, acc1, 0, 0, 0);
            }
            const int d = dta * 16 + dl;
            if (d < Dd) {
#pragma unroll
                for (int r = 0; r < 4; ++r) {
                    Out[((size_t)(b * Nn + n0 + quad * 4 + r)) * Dd + d]      = acc0[r] * inv0[r];
                    Out[((size_t)(b * Nn + n0 + 16 + quad * 4 + r)) * Dd + d] = acc1[r] * inv1[r];
                }
            }
        }
    }
}

// ---------------- launch ----------------
extern "C" void kernel_launch(void* const* d_in, const int* in_sizes, int n_in,
                              void* d_out, int out_size, void* d_ws, size_t ws_size,
                              hipStream_t stream) {
    const float* X   = (const float*)d_in[0];   // [128,512,300]
    const float* Adj = (const float*)d_in[1];   // [128,512,512]
    const float* Wq  = (const float*)d_in[2];   // [300,32]
    const float* Wk  = (const float*)d_in[3];   // [300,32]
    float* Out = (float*)d_out;                 // [128,512,300]

    ushort* Qbf  = (ushort*)d_ws;                                      // 4 MB
    ushort* Kbf  = (ushort*)((char*)d_ws + (size_t)4 * 1024 * 1024);   // 4 MB
    ushort* XbfT = (ushort*)((char*)d_ws + (size_t)8 * 1024 * 1024);   // ~39.9 MB

    proj_qk<<<dim3(Nn / KB_ROWS, Bq), 256, 0, stream>>>(X, Wq, Wk, Qbf, Kbf, XbfT);
    attn_kernel<<<dim3(Bq * Nn / TN), 256, 0, stream>>>(Adj, Qbf, Kbf, XbfT, Out);
}